// Round 1
// baseline (80.684 us; speedup 1.0000x reference)
//
#include <hip/hip_runtime.h>
#include <math.h>

#define B_ 8
#define Q_ 4096
#define N_ 128
#define H_ 256
#define W_ 256
#define EPS_ 1e-5f

// ---------------------------------------------------------------------------
// Kernel 1: per-batch point pipeline.
// Computes pixel coords, adaptive sigma (top-4 NN with jax.lax.top_k tie
// semantics: lower index first on equal distance), then evaluates the density
// ONLY at the 4 bilinear corners of each sample point (max over the batch's
// 128 Gaussians == segment_max of the full map at those pixels), and reduces
// the three loss_points partial sums per batch.
// ---------------------------------------------------------------------------
__global__ __launch_bounds__(N_) void points_kernel(
    const float* __restrict__ pred_points,  // (B,Q,2)
    const float* __restrict__ tgt_points,   // (B,N,2)
    const float* __restrict__ split_map,    // (B,Q)
    const int*   __restrict__ src_idx,      // (B,N)
    float* __restrict__ out_part)           // (B,4): sum_ld, sum_nd, cnt_nd
{
    __shared__ float spx[N_], spy[N_], sdi[N_], shalf[N_], ss2[N_];
    __shared__ float red[N_];
    const int b = blockIdx.x;
    const int n = threadIdx.x;
    const int m = b * N_ + n;

    // pixel coords (reference: tp = tgt/[H,W]; px=round(tp0*W), py=round(tp1*H))
    float t0 = tgt_points[m * 2 + 0];
    float t1 = tgt_points[m * 2 + 1];
    float px = rintf((t0 / (float)H_) * (float)W_);   // round-half-even, like jnp.round
    float py = rintf((t1 / (float)W_) * (float)H_);
    px = fminf(fmaxf(px, 0.0f), (float)(W_ - 1));
    py = fminf(fmaxf(py, 0.0f), (float)(H_ - 1));
    spx[n] = px; spy[n] = py;
    __syncthreads();

    // top-4 smallest squared distances (incl. self=0), tie-break lower index
    float d2s[4] = {INFINITY, INFINITY, INFINITY, INFINITY};
    int   ids[4] = {0x7fffffff, 0x7fffffff, 0x7fffffff, 0x7fffffff};
    for (int j = 0; j < N_; ++j) {
        float dx = px - spx[j];
        float dy = py - spy[j];
        float cd = dx * dx + dy * dy;   // integer-exact in f32
        int   ci = j;
        #pragma unroll
        for (int k = 0; k < 4; ++k) {
            bool better = (cd < d2s[k]) || (cd == d2s[k] && ci < ids[k]);
            if (better) {
                float td = d2s[k]; int ti = ids[k];
                d2s[k] = cd; ids[k] = ci;
                cd = td; ci = ti;
            }
        }
    }
    float di = sqrtf(d2s[1]);        // dists[...,1]
    sdi[n] = di;
    int nb1 = ids[1], nb2 = ids[2], nb3 = ids[3];   // nn_idx[...,1:4]
    __syncthreads();

    float dmean = ((sdi[nb1] + sdi[nb2]) + sdi[nb3]) / 3.0f;
    float d     = fminf(di, dmean);
    float sigma = fmaxf(0.4f * d, 1.0f);
    int ks = (int)(6.0f * sigma);     // trunc, like astype(int32)
    if ((ks & 1) == 0) ks += 1;
    shalf[n] = (float)(ks / 2);
    ss2[n]   = 2.0f * sigma * sigma;
    __syncthreads();

    // bilinear sample of density at this batch's sample point n
    int   src = src_idx[m];
    float sx  = pred_points[(b * Q_ + src) * 2 + 0];
    float sy  = pred_points[(b * Q_ + src) * 2 + 1];
    float gx  = fminf(fmaxf(sx * (float)W_, 0.0f), (float)(W_ - 1));
    float gy  = fminf(fmaxf(sy * (float)H_, 0.0f), (float)(H_ - 1));
    int x0 = (int)floorf(gx);
    int y0 = (int)floorf(gy);
    int x1 = min(x0 + 1, W_ - 1);
    int y1 = min(y0 + 1, H_ - 1);
    float fx = gx - (float)x0;
    float fy = gy - (float)y0;

    float d00 = 0.f, d01 = 0.f, d10 = 0.f, d11 = 0.f;
    const float cy0 = (float)y0, cy1 = (float)y1, cx0 = (float)x0, cx1 = (float)x1;
    for (int j = 0; j < N_; ++j) {
        float pxj = spx[j], pyj = spy[j], hj = shalf[j], s2j = ss2[j];
        float dy0 = cy0 - pyj, dy1 = cy1 - pyj;
        float dx0 = cx0 - pxj, dx1 = cx1 - pxj;
        bool iy0 = fabsf(dy0) <= hj, iy1 = fabsf(dy1) <= hj;
        bool ix0 = fabsf(dx0) <= hj, ix1 = fabsf(dx1) <= hj;
        float ry0 = dy0 * dy0, ry1 = dy1 * dy1;
        float rx0 = dx0 * dx0, rx1 = dx1 * dx1;
        if (iy0 && ix0) d00 = fmaxf(d00, expf(-(ry0 + rx0) / s2j));
        if (iy0 && ix1) d01 = fmaxf(d01, expf(-(ry0 + rx1) / s2j));
        if (iy1 && ix0) d10 = fmaxf(d10, expf(-(ry1 + rx0) / s2j));
        if (iy1 && ix1) d11 = fmaxf(d11, expf(-(ry1 + rx1) / s2j));
    }
    float pv = (1.f - fy) * (1.f - fx) * d00 + (1.f - fy) * fx * d01
             + fy * (1.f - fx) * d10 + fy * fx * d11;

    float lr   = 0.05f * (1.0f - pv);
    float divf = (split_map[b * Q_ + src] > 0.5f) ? 1.0f : 0.0f;
    float c_ld  = 2.0f * lr * divf;          // sum over the 2 identical columns
    float c_nd  = 2.0f * lr * (1.0f - divf);
    float c_cnt = 1.0f - divf;

    // fixed-order tree reductions (deterministic)
    float vals[3] = {c_ld, c_nd, c_cnt};
    #pragma unroll
    for (int v = 0; v < 3; ++v) {
        red[n] = vals[v];
        __syncthreads();
        for (int k = N_ / 2; k > 0; k >>= 1) {
            if (n < k) red[n] += red[n + k];
            __syncthreads();
        }
        if (n == 0) out_part[b * 4 + v] = red[0];
        __syncthreads();
    }
}

// ---------------------------------------------------------------------------
// Kernel 2: per-batch CE partial sums. target_classes via LDS bitmap.
// out_part[b] = {sum rce*w*div, sum w*div, sum rce*w*ndiv, sum w*ndiv}
// ---------------------------------------------------------------------------
__global__ __launch_bounds__(256) void ce_kernel(
    const float* __restrict__ pred_logits,  // (B,Q,2)
    const float* __restrict__ split_map,    // (B,Q)
    const int*   __restrict__ src_idx,      // (B,N)
    const int*   __restrict__ labels,       // (B,N)
    float* __restrict__ out_part)           // (B,4)
{
    __shared__ unsigned int bits[Q_ / 32];  // 128 words
    __shared__ float red[256];
    const int b = blockIdx.x;
    const int t = threadIdx.x;

    if (t < Q_ / 32) bits[t] = 0u;
    __syncthreads();
    if (t < N_) {
        int q   = src_idx[b * N_ + t];
        int lab = labels[b * N_ + t];
        if (lab != 0) atomicOr(&bits[q >> 5], 1u << (q & 31));
    }
    __syncthreads();

    float s_dn = 0.f, s_dd = 0.f, s_nn = 0.f, s_nd = 0.f;
    for (int q = t; q < Q_; q += 256) {
        float l0 = pred_logits[(b * Q_ + q) * 2 + 0];
        float l1 = pred_logits[(b * Q_ + q) * 2 + 1];
        int   tc = (bits[q >> 5] >> (q & 31)) & 1;
        float mx  = fmaxf(l0, l1);
        float lse = mx + logf(expf(l0 - mx) + expf(l1 - mx));
        float lc  = tc ? l1 : l0;
        float rce = lse - lc;                 // -log_softmax[tc]
        float w   = tc ? 1.0f : 0.5f;         // EOS weight on class 0
        float dmf = (split_map[b * Q_ + q] > 0.5f) ? 1.0f : 0.0f;
        s_dn += rce * w * dmf;
        s_dd += w * dmf;
        s_nn += rce * w * (1.0f - dmf);
        s_nd += w * (1.0f - dmf);
    }
    float vals[4] = {s_dn, s_dd, s_nn, s_nd};
    #pragma unroll
    for (int v = 0; v < 4; ++v) {
        red[t] = vals[v];
        __syncthreads();
        for (int k = 128; k > 0; k >>= 1) {
            if (t < k) red[t] += red[t + k];
            __syncthreads();
        }
        if (t == 0) out_part[b * 4 + v] = red[0];
        __syncthreads();
    }
}

// ---------------------------------------------------------------------------
// Kernel 3: MSE partial sums over (B,1,H,W), float4-vectorized.
// ---------------------------------------------------------------------------
__global__ __launch_bounds__(256) void mse_kernel(
    const float4* __restrict__ a,
    const float4* __restrict__ b4,
    float* __restrict__ part)               // (gridDim.x,)
{
    __shared__ float red[256];
    const int t = threadIdx.x;
    const int TOT4 = (B_ * H_ * W_) / 4;    // 131072
    float s = 0.f;
    for (int i = blockIdx.x * 256 + t; i < TOT4; i += gridDim.x * 256) {
        float4 x = a[i], y = b4[i];
        float d0 = x.x - y.x, d1 = x.y - y.y, d2 = x.z - y.z, d3 = x.w - y.w;
        s += d0 * d0 + d1 * d1 + d2 * d2 + d3 * d3;
    }
    red[t] = s;
    __syncthreads();
    for (int k = 128; k > 0; k >>= 1) {
        if (t < k) red[t] += red[t + k];
        __syncthreads();
    }
    if (t == 0) part[blockIdx.x] = red[0];
}

// ---------------------------------------------------------------------------
// Kernel 4: combine everything. sp/ds split = stable ascending rank of den.
// ---------------------------------------------------------------------------
__global__ __launch_bounds__(256) void final_kernel(
    const float* __restrict__ den,       // (B,)
    const float* __restrict__ pt_part,   // (B,4)
    const float* __restrict__ ce_part,   // (B,4)
    const float* __restrict__ mse_part,  // (256,)
    float* __restrict__ out)             // (3,)
{
    __shared__ float red[256];
    const int t = threadIdx.x;
    red[t] = mse_part[t];
    __syncthreads();
    for (int k = 128; k > 0; k >>= 1) {
        if (t < k) red[t] += red[t + k];
        __syncthreads();
    }
    if (t == 0) {
        float loss_maps = red[0] / (float)(B_ * H_ * W_);

        float dn[B_];
        for (int i = 0; i < B_; ++i) dn[i] = den[i];

        float num_sp = 0.f, den_sp = 0.f, num_ds = 0.f, den_ds = 0.f;
        float num_nd = 0.f, den_nd = 0.f;
        float p_sp = 0.f, p_ds = 0.f, p_nd = 0.f, cnt_nd = 0.f;
        for (int b = 0; b < B_; ++b) {
            int rank = 0;
            for (int j = 0; j < B_; ++j)
                rank += ((dn[j] < dn[b]) || (dn[j] == dn[b] && j < b)) ? 1 : 0;
            float sp  = (rank >= B_ / 2) ? 1.0f : 0.0f;   // 4 largest den
            float dsv = 1.0f - sp;
            num_sp += sp  * ce_part[b * 4 + 0];
            den_sp += sp  * ce_part[b * 4 + 1];
            num_ds += dsv * ce_part[b * 4 + 0];
            den_ds += dsv * ce_part[b * 4 + 1];
            num_nd += ce_part[b * 4 + 2];
            den_nd += ce_part[b * 4 + 3];
            p_sp   += sp  * pt_part[b * 4 + 0];
            p_ds   += dsv * pt_part[b * 4 + 0];
            p_nd   += pt_part[b * 4 + 1];
            cnt_nd += pt_part[b * 4 + 2];
        }
        float loss_ce = num_sp / (den_sp + EPS_)
                      + num_ds / (den_ds + EPS_)
                      + num_nd / (den_nd + EPS_);
        float half_cnt = (float)(N_ * (B_ / 2));   // sp_pts.sum() == ds_pts.sum() == 512
        float loss_points = p_sp / (half_cnt + EPS_)
                          + p_ds / (half_cnt + EPS_)
                          + p_nd / (cnt_nd + EPS_);
        out[0] = loss_ce;
        out[1] = loss_points;
        out[2] = loss_maps;
    }
}

extern "C" void kernel_launch(void* const* d_in, const int* in_sizes, int n_in,
                              void* d_out, int out_size, void* d_ws, size_t ws_size,
                              hipStream_t stream) {
    const float* pred_logits = (const float*)d_in[0];
    const float* pred_points = (const float*)d_in[1];
    const float* tgt_points  = (const float*)d_in[2];
    const float* split_map   = (const float*)d_in[3];
    const float* den         = (const float*)d_in[4];
    const float* prob        = (const float*)d_in[5];
    const float* prob_est    = (const float*)d_in[6];
    const int*   src_idx     = (const int*)d_in[7];
    const int*   labels      = (const int*)d_in[8];
    float* out = (float*)d_out;

    float* ws       = (float*)d_ws;
    float* pt_part  = ws;        // 32 floats
    float* ce_part  = ws + 32;   // 32 floats
    float* mse_part = ws + 64;   // 256 floats

    points_kernel<<<B_, N_, 0, stream>>>(pred_points, tgt_points, split_map,
                                         src_idx, pt_part);
    ce_kernel<<<B_, 256, 0, stream>>>(pred_logits, split_map, src_idx, labels,
                                      ce_part);
    mse_kernel<<<256, 256, 0, stream>>>((const float4*)prob,
                                        (const float4*)prob_est, mse_part);
    final_kernel<<<1, 256, 0, stream>>>(den, pt_part, ce_part, mse_part, out);
}

// Round 2
// 31.997 us; speedup vs baseline: 2.5216x; 2.5216x over previous
//
#include <hip/hip_runtime.h>
#include <math.h>

#define B_ 8
#define Q_ 4096
#define N_ 128
#define H_ 256
#define W_ 256
#define EPS_ 1e-5f
#define NBLK 64            // 8 slices per batch
#define NTHR 1024

__device__ __forceinline__ float wave_sum(float x) {
    #pragma unroll
    for (int o = 32; o > 0; o >>= 1) x += __shfl_xor(x, o, 64);
    return x;
}

// ---------------------------------------------------------------------------
// One fused kernel: pixel coords, top-4 NN + sigma (redundant per slice-block),
// density at bilinear corners for this block's 16 sample points, CE partials
// for this block's 512 queries, MSE partials. All reductions fixed-order.
// ---------------------------------------------------------------------------
__global__ __launch_bounds__(NTHR) void main_kernel(
    const float* __restrict__ pred_logits,  // (B,Q,2)
    const float* __restrict__ pred_points,  // (B,Q,2)
    const float* __restrict__ tgt_points,   // (B,N,2)
    const float* __restrict__ split_map,    // (B,Q)
    const int*   __restrict__ src_idx,      // (B,N)
    const int*   __restrict__ labels,       // (B,N)
    const float4* __restrict__ prob,
    const float4* __restrict__ prob_est,
    float* __restrict__ pt_part,            // (NBLK,4)
    float* __restrict__ ce_part,            // (NBLK,4)
    float* __restrict__ mse_part)           // (NBLK,)
{
    const int blk = blockIdx.x;
    const int b   = blk >> 3;     // batch
    const int s   = blk & 7;      // slice within batch
    const int t   = threadIdx.x;
    const int wid = t >> 6;       // wave id (16 waves)

    __shared__ float spx[N_], spy[N_], sdi[N_], shalf[N_], ss2[N_];
    __shared__ float cand_d[N_ * 8 * 4];
    __shared__ int   cand_i[N_ * 8 * 4];
    __shared__ float dmax[16 * 4 * 16];   // [p_loc][corner][chunk]
    __shared__ float dcor[16 * 4];        // [p_loc][corner]
    __shared__ float ptv[16 * 3];         // per-point c_ld, c_nd, c_cnt
    __shared__ float wred[16 * 5];        // per-wave ce[4] + mse
    __shared__ unsigned int bits[Q_ / 32];

    // ---- MSE local partial (2 float4 pairs per thread) ----
    float s_mse = 0.f;
    {
        const int TOT4 = (B_ * H_ * W_) / 4;   // 131072
        for (int i = blk * NTHR + t; i < TOT4; i += NBLK * NTHR) {
            float4 x = prob[i], y = prob_est[i];
            float d0 = x.x - y.x, d1 = x.y - y.y, d2 = x.z - y.z, d3 = x.w - y.w;
            s_mse += d0 * d0 + d1 * d1 + d2 * d2 + d3 * d3;
        }
    }

    // ---- pixel coords + bitmap zero ----
    if (t < N_) {
        float t0 = tgt_points[(b * N_ + t) * 2 + 0];
        float t1 = tgt_points[(b * N_ + t) * 2 + 1];
        float px = rintf((t0 / (float)H_) * (float)W_);
        float py = rintf((t1 / (float)W_) * (float)H_);
        spx[t] = fminf(fmaxf(px, 0.0f), (float)(W_ - 1));
        spy[t] = fminf(fmaxf(py, 0.0f), (float)(H_ - 1));
        bits[t] = 0u;   // Q_/32 == N_ == 128
    }
    __syncthreads();

    // ---- bitmap scatter + NN scan (8 scanners per point, 16 j each) ----
    if (t < N_) {
        int q   = src_idx[b * N_ + t];
        int lab = labels[b * N_ + t];
        if (lab != 0) atomicOr(&bits[q >> 5], 1u << (q & 31));
    }
    {
        const int p = t >> 3;
        const int r = t & 7;
        float px = spx[p], py = spy[p];
        float d2s[4] = {INFINITY, INFINITY, INFINITY, INFINITY};
        int   ids[4] = {0x7fffffff, 0x7fffffff, 0x7fffffff, 0x7fffffff};
        for (int j = r * 16; j < r * 16 + 16; ++j) {
            float dx = px - spx[j];
            float dy = py - spy[j];
            float cd = dx * dx + dy * dy;
            int   ci = j;
            #pragma unroll
            for (int k = 0; k < 4; ++k) {
                bool better = (cd < d2s[k]) || (cd == d2s[k] && ci < ids[k]);
                if (better) {
                    float td = d2s[k]; int ti = ids[k];
                    d2s[k] = cd; ids[k] = ci;
                    cd = td; ci = ti;
                }
            }
        }
        const int cb = (p * 8 + r) * 4;
        #pragma unroll
        for (int k = 0; k < 4; ++k) { cand_d[cb + k] = d2s[k]; cand_i[cb + k] = ids[k]; }
    }
    __syncthreads();

    // ---- merge 32 candidates -> top-4, di ----
    int nb1 = 0, nb2 = 0, nb3 = 0;
    if (t < N_) {
        float m_d[4] = {INFINITY, INFINITY, INFINITY, INFINITY};
        int   m_i[4] = {0x7fffffff, 0x7fffffff, 0x7fffffff, 0x7fffffff};
        for (int r = 0; r < 8; ++r) {
            const int cb = (t * 8 + r) * 4;
            for (int k = 0; k < 4; ++k) {
                float cd = cand_d[cb + k];
                int   ci = cand_i[cb + k];
                #pragma unroll
                for (int u = 0; u < 4; ++u) {
                    bool better = (cd < m_d[u]) || (cd == m_d[u] && ci < m_i[u]);
                    if (better) {
                        float td = m_d[u]; int ti = m_i[u];
                        m_d[u] = cd; m_i[u] = ci;
                        cd = td; ci = ti;
                    }
                }
            }
        }
        sdi[t] = sqrtf(m_d[1]);
        nb1 = m_i[1]; nb2 = m_i[2]; nb3 = m_i[3];
    }
    __syncthreads();

    // ---- sigma, half, 2*sigma^2 ----
    if (t < N_) {
        float di    = sdi[t];
        float dmean = ((sdi[nb1] + sdi[nb2]) + sdi[nb3]) / 3.0f;
        float d     = fminf(di, dmean);
        float sigma = fmaxf(0.4f * d, 1.0f);
        int ks = (int)(6.0f * sigma);
        if ((ks & 1) == 0) ks += 1;
        shalf[t] = (float)(ks / 2);
        ss2[t]   = 2.0f * sigma * sigma;
    }
    __syncthreads();

    // ---- density at 4 bilinear corners for this block's 16 points ----
    {
        const int p_loc = t >> 6;           // 0..15
        const int r     = t & 63;
        const int c     = r & 3;            // corner
        const int chunk = r >> 2;           // 0..15, 8 j each
        const int n     = s * 16 + p_loc;
        const int m     = b * N_ + n;
        int   src = src_idx[m];
        float sx  = pred_points[(b * Q_ + src) * 2 + 0];
        float sy  = pred_points[(b * Q_ + src) * 2 + 1];
        float gx  = fminf(fmaxf(sx * (float)W_, 0.0f), (float)(W_ - 1));
        float gy  = fminf(fmaxf(sy * (float)H_, 0.0f), (float)(H_ - 1));
        int x0 = (int)floorf(gx);
        int y0 = (int)floorf(gy);
        int x1 = min(x0 + 1, W_ - 1);
        int y1 = min(y0 + 1, H_ - 1);
        float cy = (float)((c & 2) ? y1 : y0);
        float cx = (float)((c & 1) ? x1 : x0);
        float lmax = 0.f;
        for (int j = chunk * 8; j < chunk * 8 + 8; ++j) {
            float dy = cy - spy[j], dx = cx - spx[j];
            float hj = shalf[j];
            if (fabsf(dy) <= hj && fabsf(dx) <= hj)
                lmax = fmaxf(lmax, expf(-(dy * dy + dx * dx) / ss2[j]));
        }
        dmax[(p_loc * 4 + c) * 16 + chunk] = lmax;
    }
    __syncthreads();

    if (t < 64) {   // reduce 16 chunks per (point, corner)
        float mx = 0.f;
        for (int k = 0; k < 16; ++k) mx = fmaxf(mx, dmax[t * 16 + k]);
        dcor[t] = mx;
    }
    __syncthreads();

    if (t < 16) {   // bilinear sample + per-point loss values
        const int n = s * 16 + t;
        const int m = b * N_ + n;
        int   src = src_idx[m];
        float sx  = pred_points[(b * Q_ + src) * 2 + 0];
        float sy  = pred_points[(b * Q_ + src) * 2 + 1];
        float gx  = fminf(fmaxf(sx * (float)W_, 0.0f), (float)(W_ - 1));
        float gy  = fminf(fmaxf(sy * (float)H_, 0.0f), (float)(H_ - 1));
        int x0 = (int)floorf(gx);
        int y0 = (int)floorf(gy);
        float fx = gx - (float)x0;
        float fy = gy - (float)y0;
        float d00 = dcor[t * 4 + 0], d01 = dcor[t * 4 + 1];
        float d10 = dcor[t * 4 + 2], d11 = dcor[t * 4 + 3];
        float pv = (1.f - fy) * (1.f - fx) * d00 + (1.f - fy) * fx * d01
                 + fy * (1.f - fx) * d10 + fy * fx * d11;
        float lr   = 0.05f * (1.0f - pv);
        float divf = (split_map[b * Q_ + src] > 0.5f) ? 1.0f : 0.0f;
        ptv[t * 3 + 0] = 2.0f * lr * divf;
        ptv[t * 3 + 1] = 2.0f * lr * (1.0f - divf);
        ptv[t * 3 + 2] = 1.0f - divf;
    }

    // ---- CE partials for this block's 512 queries (regs only) ----
    float s_dn = 0.f, s_dd = 0.f, s_nn = 0.f, s_nd = 0.f;
    if (t < 512) {
        const int q = s * 512 + t;
        float l0 = pred_logits[(b * Q_ + q) * 2 + 0];
        float l1 = pred_logits[(b * Q_ + q) * 2 + 1];
        int   tc = (bits[q >> 5] >> (q & 31)) & 1;
        float mx  = fmaxf(l0, l1);
        float lse = mx + logf(expf(l0 - mx) + expf(l1 - mx));
        float rce = lse - (tc ? l1 : l0);
        float w   = tc ? 1.0f : 0.5f;
        float dmf = (split_map[b * Q_ + q] > 0.5f) ? 1.0f : 0.0f;
        s_dn = rce * w * dmf;
        s_dd = w * dmf;
        s_nn = rce * w * (1.0f - dmf);
        s_nd = w * (1.0f - dmf);
    }

    // ---- wave butterfly reductions (fixed order, deterministic) ----
    float r0 = wave_sum(s_dn), r1 = wave_sum(s_dd);
    float r2 = wave_sum(s_nn), r3 = wave_sum(s_nd);
    float r4 = wave_sum(s_mse);
    if ((t & 63) == 0) {
        wred[wid * 5 + 0] = r0; wred[wid * 5 + 1] = r1;
        wred[wid * 5 + 2] = r2; wred[wid * 5 + 3] = r3;
        wred[wid * 5 + 4] = r4;
    }
    __syncthreads();

    if (t == 0) {
        float a0 = 0.f, a1 = 0.f, a2 = 0.f, a3 = 0.f, a4 = 0.f;
        for (int wv = 0; wv < 16; ++wv) {
            a0 += wred[wv * 5 + 0]; a1 += wred[wv * 5 + 1];
            a2 += wred[wv * 5 + 2]; a3 += wred[wv * 5 + 3];
            a4 += wred[wv * 5 + 4];
        }
        ce_part[blk * 4 + 0] = a0; ce_part[blk * 4 + 1] = a1;
        ce_part[blk * 4 + 2] = a2; ce_part[blk * 4 + 3] = a3;
        mse_part[blk] = a4;
        float p0 = 0.f, p1 = 0.f, p2 = 0.f;
        for (int k = 0; k < 16; ++k) {
            p0 += ptv[k * 3 + 0]; p1 += ptv[k * 3 + 1]; p2 += ptv[k * 3 + 2];
        }
        pt_part[blk * 4 + 0] = p0;
        pt_part[blk * 4 + 1] = p1;
        pt_part[blk * 4 + 2] = p2;
    }
}

// ---------------------------------------------------------------------------
// Final combine: den-rank split + the three losses.
// ---------------------------------------------------------------------------
__global__ __launch_bounds__(64) void final_kernel(
    const float* __restrict__ den,       // (B,)
    const float* __restrict__ pt_part,   // (NBLK,4)
    const float* __restrict__ ce_part,   // (NBLK,4)
    const float* __restrict__ mse_part,  // (NBLK,)
    float* __restrict__ out)             // (3,)
{
    if (threadIdx.x != 0) return;

    float mse = 0.f;
    for (int i = 0; i < NBLK; ++i) mse += mse_part[i];
    float loss_maps = mse / (float)(B_ * H_ * W_);

    float dn[B_];
    for (int i = 0; i < B_; ++i) dn[i] = den[i];

    float num_sp = 0.f, den_sp = 0.f, num_ds = 0.f, den_ds = 0.f;
    float num_nd = 0.f, den_nd = 0.f;
    float p_sp = 0.f, p_ds = 0.f, p_nd = 0.f, cnt_nd = 0.f;
    for (int b = 0; b < B_; ++b) {
        int rank = 0;
        for (int j = 0; j < B_; ++j)
            rank += ((dn[j] < dn[b]) || (dn[j] == dn[b] && j < b)) ? 1 : 0;
        float sp  = (rank >= B_ / 2) ? 1.0f : 0.0f;
        float dsv = 1.0f - sp;
        float c0 = 0.f, c1 = 0.f, c2 = 0.f, c3 = 0.f;
        float q0 = 0.f, q1 = 0.f, q2 = 0.f;
        for (int s = 0; s < 8; ++s) {
            int blk = b * 8 + s;
            c0 += ce_part[blk * 4 + 0]; c1 += ce_part[blk * 4 + 1];
            c2 += ce_part[blk * 4 + 2]; c3 += ce_part[blk * 4 + 3];
            q0 += pt_part[blk * 4 + 0]; q1 += pt_part[blk * 4 + 1];
            q2 += pt_part[blk * 4 + 2];
        }
        num_sp += sp  * c0;  den_sp += sp  * c1;
        num_ds += dsv * c0;  den_ds += dsv * c1;
        num_nd += c2;        den_nd += c3;
        p_sp   += sp  * q0;  p_ds   += dsv * q0;
        p_nd   += q1;        cnt_nd += q2;
    }
    float loss_ce = num_sp / (den_sp + EPS_)
                  + num_ds / (den_ds + EPS_)
                  + num_nd / (den_nd + EPS_);
    float half_cnt = (float)(N_ * (B_ / 2));
    float loss_points = p_sp / (half_cnt + EPS_)
                      + p_ds / (half_cnt + EPS_)
                      + p_nd / (cnt_nd + EPS_);
    out[0] = loss_ce;
    out[1] = loss_points;
    out[2] = loss_maps;
}

extern "C" void kernel_launch(void* const* d_in, const int* in_sizes, int n_in,
                              void* d_out, int out_size, void* d_ws, size_t ws_size,
                              hipStream_t stream) {
    const float* pred_logits = (const float*)d_in[0];
    const float* pred_points = (const float*)d_in[1];
    const float* tgt_points  = (const float*)d_in[2];
    const float* split_map   = (const float*)d_in[3];
    const float* den         = (const float*)d_in[4];
    const float* prob        = (const float*)d_in[5];
    const float* prob_est    = (const float*)d_in[6];
    const int*   src_idx     = (const int*)d_in[7];
    const int*   labels      = (const int*)d_in[8];
    float* out = (float*)d_out;

    float* ws       = (float*)d_ws;
    float* pt_part  = ws;          // 256 floats
    float* ce_part  = ws + 256;    // 256 floats
    float* mse_part = ws + 512;    // 64 floats

    main_kernel<<<NBLK, NTHR, 0, stream>>>(pred_logits, pred_points, tgt_points,
                                           split_map, src_idx, labels,
                                           (const float4*)prob,
                                           (const float4*)prob_est,
                                           pt_part, ce_part, mse_part);
    final_kernel<<<1, 64, 0, stream>>>(den, pt_part, ce_part, mse_part, out);
}

// Round 3
// 17.375 us; speedup vs baseline: 4.6437x; 1.8416x over previous
//
#include <hip/hip_runtime.h>
#include <math.h>

#define B_ 8
#define Q_ 4096
#define N_ 128
#define EPS_ 1e-5f

typedef unsigned int u32;

__device__ __forceinline__ float wave_sum64(float x) {
    #pragma unroll
    for (int o = 32; o > 0; o >>= 1) x += __shfl_xor(x, o, 64);
    return x;
}

// ---------------------------------------------------------------------------
// K1: per-batch geometry (pixel coords, top-4 NN via in-wave key merge, sigma)
// + CE partial sums. 8 blocks x 1024 threads.
// ---------------------------------------------------------------------------
__global__ __launch_bounds__(1024) void geom_ce_kernel(
    const float* __restrict__ pred_logits,  // (B,Q,2)
    const float* __restrict__ tgt_points,   // (B,N,2)
    const float* __restrict__ split_map,    // (B,Q)
    const int*   __restrict__ src_idx,      // (B,N)
    const int*   __restrict__ labels,       // (B,N)
    float4* __restrict__ ws_geom,           // (B*N): px,py,half,2s^2
    float*  __restrict__ ce_part)           // (B,4)
{
    const int b = blockIdx.x;
    const int t = threadIdx.x;
    __shared__ u32   bits[Q_ / 32];   // 128 words
    __shared__ int   spk[N_];         // (ipx<<8)|ipy
    __shared__ float sdi[N_];
    __shared__ float wred[16 * 4];

    // hoisted global loads (latency hides under bitmap/NN phases)
    const float4* logitsv = (const float4*)pred_logits;
    const float4* splitv  = (const float4*)split_map;
    float4 L0 = logitsv[b * 2048 + 2 * t];
    float4 L1 = logitsv[b * 2048 + 2 * t + 1];
    float4 S4 = splitv[b * 1024 + t];

    float2 tp = make_float2(0.f, 0.f);
    int src = 0, lab = 0;
    if (t < N_) {
        tp  = ((const float2*)tgt_points)[b * N_ + t];
        src = src_idx[b * N_ + t];
        lab = labels[b * N_ + t];
        bits[t] = 0u;
    }
    __syncthreads();   // A: bits zeroed

    if (t < N_) {
        float px = rintf((tp.x / 256.f) * 256.f);   // round-half-even
        float py = rintf((tp.y / 256.f) * 256.f);
        px = fminf(fmaxf(px, 0.f), 255.f);
        py = fminf(fmaxf(py, 0.f), 255.f);
        spk[t] = (((int)px) << 8) | ((int)py);
        if (lab != 0) atomicOr(&bits[src >> 5], 1u << (src & 31));
    }
    __syncthreads();   // B: spk + bits ready

    // ---- NN top-4: 8 lanes per point, integer keys (d2<<7)|j ----
    const int p = t >> 3;
    const int r = t & 7;
    int nb1, nb2, nb3;
    float di;
    {
        int mypk = spk[p];
        int myx = mypk >> 8, myy = mypk & 255;
        u32 s0 = 0x7fffffffu, s1 = 0x7fffffffu, s2 = 0x7fffffffu, s3 = 0x7fffffffu;
        #pragma unroll
        for (int jj = 0; jj < 16; ++jj) {
            int j  = jj * 8 + r;               // interleaved: LDS conflict-free
            int pk = spk[j];
            int dx = (pk >> 8) - myx;
            int dy = (pk & 255) - myy;
            u32 u = ((u32)(dx * dx + dy * dy) << 7) | (u32)j;
            u32 m0 = min(s0, u); u = max(s0, u); s0 = m0;
            u32 m1 = min(s1, u); u = max(s1, u); s1 = m1;
            u32 m2 = min(s2, u); u = max(s2, u); s2 = m2;
            s3 = min(s3, u);
        }
        // merge sorted 4-lists across the 8-lane group (keep-low bitonic)
        #pragma unroll
        for (int m = 1; m <= 4; m <<= 1) {
            u32 q0 = (u32)__shfl_xor((int)s0, m, 64);
            u32 q1 = (u32)__shfl_xor((int)s1, m, 64);
            u32 q2 = (u32)__shfl_xor((int)s2, m, 64);
            u32 q3 = (u32)__shfl_xor((int)s3, m, 64);
            u32 l0 = min(s0, q3), l1 = min(s1, q2), l2 = min(s2, q1), l3 = min(s3, q0);
            u32 a0 = min(l0, l2), a2 = max(l0, l2);
            u32 a1 = min(l1, l3), a3 = max(l1, l3);
            s0 = min(a0, a1); s1 = max(a0, a1);
            s2 = min(a2, a3); s3 = max(a2, a3);
        }
        di  = sqrtf((float)(s1 >> 7));
        nb1 = (int)(s1 & 127u); nb2 = (int)(s2 & 127u); nb3 = (int)(s3 & 127u);
        if (r == 0) sdi[p] = di;
    }
    __syncthreads();   // C: sdi ready

    if (r == 0) {
        float dmean = ((sdi[nb1] + sdi[nb2]) + sdi[nb3]) / 3.0f;
        float d     = fminf(di, dmean);
        float sigma = fmaxf(0.4f * d, 1.0f);
        int ks = (int)(6.0f * sigma);
        if ((ks & 1) == 0) ks += 1;
        int pk = spk[p];
        ws_geom[b * N_ + p] = make_float4((float)(pk >> 8), (float)(pk & 255),
                                          (float)(ks / 2), 2.0f * sigma * sigma);
    }

    // ---- CE partials: 4 queries per thread (preloaded regs) ----
    float lq0[4] = {L0.x, L0.z, L1.x, L1.z};
    float lq1[4] = {L0.y, L0.w, L1.y, L1.w};
    float sm4[4] = {S4.x, S4.y, S4.z, S4.w};
    float s_dn = 0.f, s_dd = 0.f, s_nn = 0.f, s_nd = 0.f;
    #pragma unroll
    for (int k = 0; k < 4; ++k) {
        int q = 4 * t + k;
        float l0 = lq0[k], l1 = lq1[k];
        int   tc = (bits[q >> 5] >> (q & 31)) & 1;
        float mx  = fmaxf(l0, l1);
        float lse = mx + logf(expf(l0 - mx) + expf(l1 - mx));
        float rce = lse - (tc ? l1 : l0);
        float w   = tc ? 1.0f : 0.5f;
        float dmf = (sm4[k] > 0.5f) ? 1.0f : 0.0f;
        s_dn += rce * w * dmf;
        s_dd += w * dmf;
        s_nn += rce * w * (1.0f - dmf);
        s_nd += w * (1.0f - dmf);
    }
    float r0 = wave_sum64(s_dn), r1 = wave_sum64(s_dd);
    float r2 = wave_sum64(s_nn), r3 = wave_sum64(s_nd);
    const int wid = t >> 6;
    if ((t & 63) == 0) {
        wred[wid * 4 + 0] = r0; wred[wid * 4 + 1] = r1;
        wred[wid * 4 + 2] = r2; wred[wid * 4 + 3] = r3;
    }
    __syncthreads();   // D
    if (t == 0) {
        float a0 = 0.f, a1 = 0.f, a2 = 0.f, a3 = 0.f;
        for (int wv = 0; wv < 16; ++wv) {
            a0 += wred[wv * 4 + 0]; a1 += wred[wv * 4 + 1];
            a2 += wred[wv * 4 + 2]; a3 += wred[wv * 4 + 3];
        }
        ce_part[b * 4 + 0] = a0; ce_part[b * 4 + 1] = a1;
        ce_part[b * 4 + 2] = a2; ce_part[b * 4 + 3] = a3;
    }
}

// ---------------------------------------------------------------------------
// K2: one wave per sample point: density at 4 bilinear corners (max over the
// batch's 128 Gaussians) + per-point loss values + MSE grid-stride partial.
// 1024 blocks x 64 threads.
// ---------------------------------------------------------------------------
__global__ __launch_bounds__(64) void density_kernel(
    const float* __restrict__ pred_points,  // (B,Q,2)
    const float* __restrict__ split_map,    // (B,Q)
    const int*   __restrict__ src_idx,      // (B,N)
    const float4* __restrict__ prob,
    const float4* __restrict__ prob_est,
    const float4* __restrict__ ws_geom,     // (B*N)
    float4* __restrict__ ptv4)              // (B*N): c_ld,c_nd,c_cnt,mse
{
    const int g = blockIdx.x;      // global point index
    const int b = g >> 7;
    const int l = threadIdx.x;     // 0..63

    // MSE partial: 2 float4-pairs per lane, full coverage over 1024 blocks
    float msum = 0.f;
    {
        int i0 = g * 64 + l;
        float4 x0 = prob[i0],          y0 = prob_est[i0];
        float4 x1 = prob[i0 + 65536],  y1 = prob_est[i0 + 65536];
        float d;
        d = x0.x - y0.x; msum += d * d;  d = x0.y - y0.y; msum += d * d;
        d = x0.z - y0.z; msum += d * d;  d = x0.w - y0.w; msum += d * d;
        d = x1.x - y1.x; msum += d * d;  d = x1.y - y1.y; msum += d * d;
        d = x1.z - y1.z; msum += d * d;  d = x1.w - y1.w; msum += d * d;
    }

    float4 G0 = ws_geom[b * N_ + l];
    float4 G1 = ws_geom[b * N_ + 64 + l];

    int   src = src_idx[g];
    float sx  = pred_points[(b * Q_ + src) * 2 + 0];
    float sy  = pred_points[(b * Q_ + src) * 2 + 1];
    float spl = split_map[b * Q_ + src];
    float gx  = fminf(fmaxf(sx * 256.f, 0.f), 255.f);
    float gy  = fminf(fmaxf(sy * 256.f, 0.f), 255.f);
    int x0 = (int)floorf(gx), y0 = (int)floorf(gy);
    int x1 = min(x0 + 1, 255), y1 = min(y0 + 1, 255);
    float fx = gx - (float)x0, fy = gy - (float)y0;
    float cx0 = (float)x0, cx1 = (float)x1, cy0 = (float)y0, cy1 = (float)y1;

    float c00 = 0.f, c01 = 0.f, c10 = 0.f, c11 = 0.f;
    #pragma unroll
    for (int k = 0; k < 2; ++k) {
        float4 G = k ? G1 : G0;
        float h = G.z, s2 = G.w;
        float dy0 = cy0 - G.y, dy1 = cy1 - G.y;
        float dx0 = cx0 - G.x, dx1 = cx1 - G.x;
        bool iy0 = fabsf(dy0) <= h, iy1 = fabsf(dy1) <= h;
        bool ix0 = fabsf(dx0) <= h, ix1 = fabsf(dx1) <= h;
        if (iy0 && ix0) c00 = fmaxf(c00, expf(-(dy0 * dy0 + dx0 * dx0) / s2));
        if (iy0 && ix1) c01 = fmaxf(c01, expf(-(dy0 * dy0 + dx1 * dx1) / s2));
        if (iy1 && ix0) c10 = fmaxf(c10, expf(-(dy1 * dy1 + dx0 * dx0) / s2));
        if (iy1 && ix1) c11 = fmaxf(c11, expf(-(dy1 * dy1 + dx1 * dx1) / s2));
    }
    #pragma unroll
    for (int o = 32; o > 0; o >>= 1) {
        c00 = fmaxf(c00, __shfl_xor(c00, o, 64));
        c01 = fmaxf(c01, __shfl_xor(c01, o, 64));
        c10 = fmaxf(c10, __shfl_xor(c10, o, 64));
        c11 = fmaxf(c11, __shfl_xor(c11, o, 64));
    }
    msum = wave_sum64(msum);

    if (l == 0) {
        float pv = (1.f - fy) * (1.f - fx) * c00 + (1.f - fy) * fx * c01
                 + fy * (1.f - fx) * c10 + fy * fx * c11;
        float lr   = 0.05f * (1.0f - pv);
        float divf = (spl > 0.5f) ? 1.0f : 0.0f;
        ptv4[g] = make_float4(2.0f * lr * divf, 2.0f * lr * (1.0f - divf),
                              1.0f - divf, msum);
    }
}

// ---------------------------------------------------------------------------
// K3: segmented reduce of the 1024 per-point float4 partials + final combine.
// ---------------------------------------------------------------------------
__global__ __launch_bounds__(1024) void final_kernel(
    const float*  __restrict__ den,      // (B,)
    const float4* __restrict__ ptv4,     // (B*N)
    const float*  __restrict__ ce_part,  // (B,4)
    float* __restrict__ out)             // (3,)
{
    __shared__ float4 red[1024];
    const int t = threadIdx.x;
    red[t] = ptv4[t];
    __syncthreads();
    for (int k = 64; k > 0; k >>= 1) {
        if ((t & 127) < k) {
            float4 a = red[t], c = red[t + k];
            red[t] = make_float4(a.x + c.x, a.y + c.y, a.z + c.z, a.w + c.w);
        }
        __syncthreads();
    }
    if (t == 0) {
        float dn[B_];
        for (int i = 0; i < B_; ++i) dn[i] = den[i];

        float mse = 0.f;
        float num_sp = 0.f, den_sp = 0.f, num_ds = 0.f, den_ds = 0.f;
        float num_nd = 0.f, den_nd = 0.f;
        float p_sp = 0.f, p_ds = 0.f, p_nd = 0.f, cnt_nd = 0.f;
        for (int b = 0; b < B_; ++b) {
            int rank = 0;
            for (int j = 0; j < B_; ++j)
                rank += ((dn[j] < dn[b]) || (dn[j] == dn[b] && j < b)) ? 1 : 0;
            float sp  = (rank >= B_ / 2) ? 1.0f : 0.0f;
            float dsv = 1.0f - sp;
            float4 s = red[b * N_];
            mse += s.w;
            float c0 = ce_part[b * 4 + 0], c1 = ce_part[b * 4 + 1];
            float c2 = ce_part[b * 4 + 2], c3 = ce_part[b * 4 + 3];
            num_sp += sp  * c0;  den_sp += sp  * c1;
            num_ds += dsv * c0;  den_ds += dsv * c1;
            num_nd += c2;        den_nd += c3;
            p_sp   += sp  * s.x; p_ds   += dsv * s.x;
            p_nd   += s.y;       cnt_nd += s.z;
        }
        float loss_ce = num_sp / (den_sp + EPS_)
                      + num_ds / (den_ds + EPS_)
                      + num_nd / (den_nd + EPS_);
        float half_cnt = (float)(N_ * (B_ / 2));   // sp/ds point counts = 512
        float loss_points = p_sp / (half_cnt + EPS_)
                          + p_ds / (half_cnt + EPS_)
                          + p_nd / (cnt_nd + EPS_);
        out[0] = loss_ce;
        out[1] = loss_points;
        out[2] = mse / (float)(B_ * 256 * 256);
    }
}

extern "C" void kernel_launch(void* const* d_in, const int* in_sizes, int n_in,
                              void* d_out, int out_size, void* d_ws, size_t ws_size,
                              hipStream_t stream) {
    const float* pred_logits = (const float*)d_in[0];
    const float* pred_points = (const float*)d_in[1];
    const float* tgt_points  = (const float*)d_in[2];
    const float* split_map   = (const float*)d_in[3];
    const float* den         = (const float*)d_in[4];
    const float* prob        = (const float*)d_in[5];
    const float* prob_est    = (const float*)d_in[6];
    const int*   src_idx     = (const int*)d_in[7];
    const int*   labels      = (const int*)d_in[8];
    float* out = (float*)d_out;

    char* wsb = (char*)d_ws;
    float4* ws_geom = (float4*)wsb;                 // 1024 * 16 B
    float4* ptv4    = (float4*)(wsb + 16384);       // 1024 * 16 B
    float*  ce_part = (float*)(wsb + 32768);        // 32 floats

    geom_ce_kernel<<<B_, 1024, 0, stream>>>(pred_logits, tgt_points, split_map,
                                            src_idx, labels, ws_geom, ce_part);
    density_kernel<<<B_ * N_, 64, 0, stream>>>(pred_points, split_map, src_idx,
                                               (const float4*)prob,
                                               (const float4*)prob_est,
                                               ws_geom, ptv4);
    final_kernel<<<1, 1024, 0, stream>>>(den, ptv4, ce_part, out);
}